// Round 4
// baseline (302.818 us; speedup 1.0000x reference)
//
#include <hip/hip_runtime.h>
#include <stdint.h>

// x: (32, 256, 58, 58) f32 binary {0,1};  w: (256, 256, 3, 3) f32
// out: (32, 256, 56, 56) f32 = alpha[o]*(2S - 2304), S = XNOR matches
// out = fma(-2*alpha[o], P, 2304*alpha[o]),  P = popcount(xbits ^ wbits)

#define BATCH 32
#define C_IN 256
#define OCH 256
#define HIN 58
#define WIN2 58
#define HOUT 56
#define WOUT 56
#define TAPS 9
#define WWORDS 8            // 256 channels / 32 bits
#define HWIN (HIN * WIN2)   // 3364
#define HWOUT (HOUT * WOUT) // 3136
#define NPOS (BATCH * HWIN) // 107648

typedef unsigned int u32x8 __attribute__((ext_vector_type(8)));

// Fused accumulate-popcount: d = popc(s0) + d (R3: -18%, verified).
#define BCNT0(v) asm("v_bcnt_u32_b32 %0, %1, %0" : "+v"(a0) : "v"(v))
#define BCNT1(v) asm("v_bcnt_u32_b32 %0, %1, %0" : "+v"(a1) : "v"(v))

// ---------------------------------------------------------------------------
// Kernel 1: bit-pack x along channels. Thread ↔ (position p, word-pair wp).
// Reads 64B-coalesced per (wp,j) group; writes fully contiguous uint2/wave.
// ---------------------------------------------------------------------------
__global__ __launch_bounds__(256) void pack_x_kernel(
    const float* __restrict__ x, uint32_t* __restrict__ xp)
{
    int t = blockIdx.x * 256 + threadIdx.x;      // 1682 blocks exactly
    int p  = t >> 2;                             // position in [0, NPOS)
    int wp = t & 3;                              // word pair
    int b = p / HWIN;
    int r = p - b * HWIN;
    const float* xb = x + ((size_t)(b * C_IN + wp * 64)) * HWIN + r;
    uint32_t m0 = 0u, m1 = 0u;
    #pragma unroll
    for (int j = 0; j < 32; ++j) {
        float v0 = xb[(size_t)j * HWIN];
        float v1 = xb[(size_t)(j + 32) * HWIN];
        m0 |= (v0 > 0.5f ? 1u : 0u) << j;        // word 2wp,   bit j = ch 64wp+j
        m1 |= (v1 > 0.5f ? 1u : 0u) << j;        // word 2wp+1, bit j = ch 64wp+32+j
    }
    *(uint2*)(xp + (size_t)p * WWORDS + wp * 2) = make_uint2(m0, m1);
}

// ---------------------------------------------------------------------------
// Kernel 2: pack weights O-MINOR: wq[(tap*8 + word)*256 + o] so the main
// kernel's per-lane (lane = o) weight loads are stride-1 coalesced.
// Also per-o scale/bias.
// ---------------------------------------------------------------------------
__global__ __launch_bounds__(256) void pack_w_kernel(
    const float* __restrict__ wt, uint32_t* __restrict__ wq,
    float* __restrict__ sA, float* __restrict__ sB)
{
    int o = blockIdx.x;
    int c = threadIdx.x;
    const float* wb = wt + ((size_t)o * C_IN + c) * TAPS;
    float wv[TAPS];
    float s = 0.f;
    #pragma unroll
    for (int t = 0; t < TAPS; ++t) {
        wv[t] = wb[t];
        s += fabsf(wv[t]);
    }
    int wave = c >> 6, lane = c & 63;
    #pragma unroll
    for (int t = 0; t < TAPS; ++t) {
        unsigned long long m = __ballot(wv[t] >= 0.0f);
        if (lane == 0) {
            // word index w2 = wave*2 holds channels wave*64..+31 (bit j = ch)
            wq[(size_t)(t * 8 + wave * 2)     * OCH + o] = (uint32_t)m;
            wq[(size_t)(t * 8 + wave * 2 + 1) * OCH + o] = (uint32_t)(m >> 32);
        }
    }
    __shared__ float red[256];
    red[c] = s;
    __syncthreads();
    for (int off = 128; off > 0; off >>= 1) {
        if (c < off) red[c] += red[c + off];
        __syncthreads();
    }
    if (c == 0) {
        float alpha = red[0] / (float)(C_IN * HWIN);   // n = C*H*W per reference
        sA[o] = -2.0f * alpha;
        sB[o] = (float)(C_IN * TAPS) * alpha;          // 2304 * alpha
    }
}

// ---------------------------------------------------------------------------
// Kernel 3: main — R7 restructure: LANE = OUTPUT CHANNEL.
// R3 diagnosis: 123.7us vs 47us VALU floor; gap = weight operand delivery
// (LDS return bus in R0/R1, K$ thrash of 72KB wq across 8 o-groups/CU in
// R2/R3 — all ~150us). Inverting the mapping makes weights LOOP-INVARIANT
// PER-LANE: 72 dwords loaded ONCE into VGPRs, zero weight traffic in the
// hot loop. The x-window becomes wave-uniform per position -> streamed via
// s_load_dwordx8 from K$ (working set ~5.5KB/wave, K$-resident; each row's
// reload for pos+1 issues right after that row's 48 VALU consume it, so K$
// latency hides under the next 96 VALU).
// Block: 64 o (blockIdx.y of 4 o-groups) x one output row (b,oy); wave w
// handles positions [14w, 14w+14). Inner: 2 VALU/word exactly (v_xor v,s,v
// + fused v_bcnt), two chains for dep-latency headroom.
// Store fix (o-per-lane stores are 64-segment): results staged in LDS
// [64][57] (pad-57: stride 25 mod 32, bijective -> inherent 2-way = free)
// then flushed coalesced.
// Tail note: the last position's pipelined reload reads 32B past xp's end —
// lands in wq (same workspace, allocated), values never consumed.
// ---------------------------------------------------------------------------
__global__ __launch_bounds__(256, 5) void xnor_main_kernel(
    const uint32_t* __restrict__ xp, const uint32_t* __restrict__ wq,
    const float* __restrict__ sA, const float* __restrict__ sB,
    float* __restrict__ out)
{
    __shared__ float olds[64 * 57];              // 14,592 B

    int rj = blockIdx.x;                         // row-job 0..1791
    int b  = rj / HOUT;
    int oy = rj - b * HOUT;
    int obase = blockIdx.y * 64;
    int lane = threadIdx.x & 63;
    int wv_id = __builtin_amdgcn_readfirstlane((int)(threadIdx.x >> 6));
    int o = obase + lane;

    // Weights resident in VGPRs: 72 dwords per lane, coalesced stride-1.
    uint32_t wreg[72];
    #pragma unroll
    for (int i = 0; i < 72; ++i)
        wreg[i] = wq[(size_t)i * OCH + o];
    float sAv = sA[o];
    float sBv = sB[o];

    int ox0 = wv_id * 14;                        // this wave's first position

    // Wave-uniform row pointers (all factors uniform -> s_load path).
    const uint32_t* r0 = xp + (((size_t)b * HIN + oy + 0) * WIN2 + ox0) * WWORDS;
    const uint32_t* r1 = xp + (((size_t)b * HIN + oy + 1) * WIN2 + ox0) * WWORDS;
    const uint32_t* r2 = xp + (((size_t)b * HIN + oy + 2) * WIN2 + ox0) * WWORDS;

    // Window: rows 0..2 x cols dx=0..2, 8 words each (72 SGPRs).
    u32x8 W0a = *(const u32x8*)(r0);
    u32x8 W0b = *(const u32x8*)(r0 + 8);
    u32x8 W0c = *(const u32x8*)(r0 + 16);
    u32x8 W1a = *(const u32x8*)(r1);
    u32x8 W1b = *(const u32x8*)(r1 + 8);
    u32x8 W1c = *(const u32x8*)(r1 + 16);
    u32x8 W2a = *(const u32x8*)(r2);
    u32x8 W2b = *(const u32x8*)(r2 + 8);
    u32x8 W2c = *(const u32x8*)(r2 + 16);

    #pragma unroll 1
    for (int i = 0; i < 14; ++i) {
        uint32_t a0 = 0u, a1 = 0u, t;
        // ---- row 0: taps 0,1,2 ---- consume, then reload for pos+1
        #pragma unroll
        for (int k = 0; k < 8; ++k) { t = W0a[k] ^ wreg[0 * 8 + k]; BCNT0(t); }
        #pragma unroll
        for (int k = 0; k < 8; ++k) { t = W0b[k] ^ wreg[1 * 8 + k]; BCNT1(t); }
        #pragma unroll
        for (int k = 0; k < 8; ++k) { t = W0c[k] ^ wreg[2 * 8 + k]; BCNT0(t); }
        r0 += 8;
        W0a = *(const u32x8*)(r0);
        W0b = *(const u32x8*)(r0 + 8);
        W0c = *(const u32x8*)(r0 + 16);
        // ---- row 1: taps 3,4,5 ----
        #pragma unroll
        for (int k = 0; k < 8; ++k) { t = W1a[k] ^ wreg[3 * 8 + k]; BCNT1(t); }
        #pragma unroll
        for (int k = 0; k < 8; ++k) { t = W1b[k] ^ wreg[4 * 8 + k]; BCNT0(t); }
        #pragma unroll
        for (int k = 0; k < 8; ++k) { t = W1c[k] ^ wreg[5 * 8 + k]; BCNT1(t); }
        r1 += 8;
        W1a = *(const u32x8*)(r1);
        W1b = *(const u32x8*)(r1 + 8);
        W1c = *(const u32x8*)(r1 + 16);
        // ---- row 2: taps 6,7,8 ----
        #pragma unroll
        for (int k = 0; k < 8; ++k) { t = W2a[k] ^ wreg[6 * 8 + k]; BCNT0(t); }
        #pragma unroll
        for (int k = 0; k < 8; ++k) { t = W2b[k] ^ wreg[7 * 8 + k]; BCNT1(t); }
        #pragma unroll
        for (int k = 0; k < 8; ++k) { t = W2c[k] ^ wreg[8 * 8 + k]; BCNT0(t); }
        r2 += 8;
        W2a = *(const u32x8*)(r2);
        W2b = *(const u32x8*)(r2 + 8);
        W2c = *(const u32x8*)(r2 + 16);

        float P = (float)(a0 + a1);
        olds[lane * 57 + (ox0 + i)] = fmaf(sAv, P, sBv);
    }

    __syncthreads();

    // Coalesced flush: 64 o-rows x 56 positions = 3584 f32 by 256 threads.
    size_t obb = ((size_t)b * OCH + obase) * HWOUT + (size_t)oy * WOUT;
    int tau = threadIdx.x;
    #pragma unroll 1
    for (int i = 0; i < 14; ++i) {
        int flat = i * 256 + tau;                // 0..3583
        int op = flat / 56;
        int pp = flat - op * 56;
        out[obb + (size_t)op * HWOUT + pp] = olds[op * 57 + pp];
    }
}

// ---------------------------------------------------------------------------
extern "C" void kernel_launch(void* const* d_in, const int* in_sizes, int n_in,
                              void* d_out, int out_size, void* d_ws, size_t ws_size,
                              hipStream_t stream)
{
    const float* x  = (const float*)d_in[0];
    const float* wt = (const float*)d_in[1];
    float* out = (float*)d_out;

    char* ws = (char*)d_ws;
    uint32_t* xp = (uint32_t*)ws;                               // 3,444,736 B
    uint32_t* wq = (uint32_t*)(ws + 3444736);                   //    73,728 B
    float*    sA = (float*)(ws + 3444736 + 73728);              //     1,024 B
    float*    sB = (float*)(ws + 3444736 + 73728 + 1024);       //     1,024 B

    // 1) pack x: 430,592 threads / 256 = 1682 blocks exactly
    pack_x_kernel<<<dim3(1682), dim3(256), 0, stream>>>(x, xp);

    // 2) pack weights (o-minor) + scales
    pack_w_kernel<<<dim3(OCH), dim3(256), 0, stream>>>(wt, wq, sA, sB);

    // 3) main: 1792 row-jobs x 4 o-groups of 64
    xnor_main_kernel<<<dim3(1792, 4), dim3(256), 0, stream>>>(xp, wq, sA, sB, out);
}

// Round 5
// 301.708 us; speedup vs baseline: 1.0037x; 1.0037x over previous
//
#include <hip/hip_runtime.h>
#include <stdint.h>

// x: (32, 256, 58, 58) f32 binary {0,1};  w: (256, 256, 3, 3) f32
// out: (32, 256, 56, 56) f32 = alpha[o]*(2S - 2304), S = XNOR matches
// out = fma(-2*alpha[o], P, 2304*alpha[o]),  P = popcount(xbits ^ wbits)

#define BATCH 32
#define C_IN 256
#define OCH 256
#define HIN 58
#define WIN2 58
#define HOUT 56
#define WOUT 56
#define TAPS 9
#define WWORDS 8            // 256 channels / 32 bits
#define HWIN (HIN * WIN2)   // 3364
#define HWOUT (HOUT * WOUT) // 3136
#define NPOS (BATCH * HWIN) // 107648

typedef unsigned int u32x8 __attribute__((ext_vector_type(8)));

// Fused accumulate-popcount: d = popc(s0) + d (R3: -18%, verified).
#define BCNT0(v) asm("v_bcnt_u32_b32 %0, %1, %0" : "+v"(a0) : "v"(v))
#define BCNT1(v) asm("v_bcnt_u32_b32 %0, %1, %0" : "+v"(a1) : "v"(v))

// ---------------------------------------------------------------------------
// Kernel 1: bit-pack x along channels. Thread ↔ (position p, word-pair wp).
// Reads 64B-coalesced per (wp,j) group; writes fully contiguous uint2/wave.
// ---------------------------------------------------------------------------
__global__ __launch_bounds__(256) void pack_x_kernel(
    const float* __restrict__ x, uint32_t* __restrict__ xp)
{
    int t = blockIdx.x * 256 + threadIdx.x;      // 1682 blocks exactly
    int p  = t >> 2;                             // position in [0, NPOS)
    int wp = t & 3;                              // word pair
    int b = p / HWIN;
    int r = p - b * HWIN;
    const float* xb = x + ((size_t)(b * C_IN + wp * 64)) * HWIN + r;
    uint32_t m0 = 0u, m1 = 0u;
    #pragma unroll
    for (int j = 0; j < 32; ++j) {
        float v0 = xb[(size_t)j * HWIN];
        float v1 = xb[(size_t)(j + 32) * HWIN];
        m0 |= (v0 > 0.5f ? 1u : 0u) << j;        // word 2wp,   bit j = ch 64wp+j
        m1 |= (v1 > 0.5f ? 1u : 0u) << j;        // word 2wp+1, bit j = ch 64wp+32+j
    }
    *(uint2*)(xp + (size_t)p * WWORDS + wp * 2) = make_uint2(m0, m1);
}

// ---------------------------------------------------------------------------
// Kernel 2: pack weights O-MINOR: wq[(tap*8 + word)*256 + o] so the main
// kernel's per-lane (lane = o) weight loads are stride-1 coalesced.
// Also per-o scale/bias.
// ---------------------------------------------------------------------------
__global__ __launch_bounds__(256) void pack_w_kernel(
    const float* __restrict__ wt, uint32_t* __restrict__ wq,
    float* __restrict__ sA, float* __restrict__ sB)
{
    int o = blockIdx.x;
    int c = threadIdx.x;
    const float* wb = wt + ((size_t)o * C_IN + c) * TAPS;
    float wv[TAPS];
    float s = 0.f;
    #pragma unroll
    for (int t = 0; t < TAPS; ++t) {
        wv[t] = wb[t];
        s += fabsf(wv[t]);
    }
    int wave = c >> 6, lane = c & 63;
    #pragma unroll
    for (int t = 0; t < TAPS; ++t) {
        unsigned long long m = __ballot(wv[t] >= 0.0f);
        if (lane == 0) {
            // word index w2 = wave*2 holds channels wave*64..+31 (bit j = ch)
            wq[(size_t)(t * 8 + wave * 2)     * OCH + o] = (uint32_t)m;
            wq[(size_t)(t * 8 + wave * 2 + 1) * OCH + o] = (uint32_t)(m >> 32);
        }
    }
    __shared__ float red[256];
    red[c] = s;
    __syncthreads();
    for (int off = 128; off > 0; off >>= 1) {
        if (c < off) red[c] += red[c + off];
        __syncthreads();
    }
    if (c == 0) {
        float alpha = red[0] / (float)(C_IN * HWIN);   // n = C*H*W per reference
        sA[o] = -2.0f * alpha;
        sB[o] = (float)(C_IN * TAPS) * alpha;          // 2304 * alpha
    }
}

// ---------------------------------------------------------------------------
// Kernel 3: main — lane = output channel; weights VGPR-resident.
// R8 A/B vs R7: __launch_bounds__ (256,5) -> (256,4). R7's counters showed
// VGPR_Count=40 < 72: the ~102-reg unified budget forced the 72 weight
// words out of arch VGPRs (AGPR round-trip or in-loop reload), costing
// ~+1 VALU/word -> measured VALU-busy = 1.48x essential at the ~1.5GHz
// sustained clock. 128-reg budget fits 72 wreg + temps (~100) cleanly;
// witness: VGPR_Count >= 96. X-window stays scalarized (SGPR=96 in R7:
// 72 window SGPRs + addressing), streamed as s_load_dwordx8 from K$,
// reloaded per position (SALU/SMEM only, no VALU cost), latency hidden
// under 144 VALU per position. Inner loop: exactly 1 v_xor(v,s,v) +
// 1 fused v_bcnt per 32-channel word, two acc chains.
// Store: o-per-lane stores are 64-segment, so stage in LDS [64][57]
// (stride 57: (l*57)%32 bijective*2 -> inherent 2-way = free) and flush
// coalesced.
// Tail note: the last position's pipelined reload reads 32B past xp's end —
// lands in wq (same workspace, allocated), values never consumed.
// ---------------------------------------------------------------------------
__global__ __launch_bounds__(256, 4) void xnor_main_kernel(
    const uint32_t* __restrict__ xp, const uint32_t* __restrict__ wq,
    const float* __restrict__ sA, const float* __restrict__ sB,
    float* __restrict__ out)
{
    __shared__ float olds[64 * 57];              // 14,592 B

    int rj = blockIdx.x;                         // row-job 0..1791
    int b  = rj / HOUT;
    int oy = rj - b * HOUT;
    int obase = blockIdx.y * 64;
    int lane = threadIdx.x & 63;
    int wv_id = __builtin_amdgcn_readfirstlane((int)(threadIdx.x >> 6));
    int o = obase + lane;

    // Weights resident in VGPRs: 72 dwords per lane, coalesced stride-1.
    uint32_t wreg[72];
    #pragma unroll
    for (int i = 0; i < 72; ++i)
        wreg[i] = wq[(size_t)i * OCH + o];
    float sAv = sA[o];
    float sBv = sB[o];

    int ox0 = wv_id * 14;                        // this wave's first position

    // Wave-uniform row pointers (all factors uniform -> s_load path).
    const uint32_t* r0 = xp + (((size_t)b * HIN + oy + 0) * WIN2 + ox0) * WWORDS;
    const uint32_t* r1 = xp + (((size_t)b * HIN + oy + 1) * WIN2 + ox0) * WWORDS;
    const uint32_t* r2 = xp + (((size_t)b * HIN + oy + 2) * WIN2 + ox0) * WWORDS;

    // Window: rows 0..2 x cols dx=0..2, 8 words each (72 SGPRs).
    u32x8 W0a = *(const u32x8*)(r0);
    u32x8 W0b = *(const u32x8*)(r0 + 8);
    u32x8 W0c = *(const u32x8*)(r0 + 16);
    u32x8 W1a = *(const u32x8*)(r1);
    u32x8 W1b = *(const u32x8*)(r1 + 8);
    u32x8 W1c = *(const u32x8*)(r1 + 16);
    u32x8 W2a = *(const u32x8*)(r2);
    u32x8 W2b = *(const u32x8*)(r2 + 8);
    u32x8 W2c = *(const u32x8*)(r2 + 16);

    #pragma unroll 1
    for (int i = 0; i < 14; ++i) {
        uint32_t a0 = 0u, a1 = 0u, t;
        // ---- row 0: taps 0,1,2 ---- consume, then reload for pos+1
        #pragma unroll
        for (int k = 0; k < 8; ++k) { t = W0a[k] ^ wreg[0 * 8 + k]; BCNT0(t); }
        #pragma unroll
        for (int k = 0; k < 8; ++k) { t = W0b[k] ^ wreg[1 * 8 + k]; BCNT1(t); }
        #pragma unroll
        for (int k = 0; k < 8; ++k) { t = W0c[k] ^ wreg[2 * 8 + k]; BCNT0(t); }
        r0 += 8;
        W0a = *(const u32x8*)(r0);
        W0b = *(const u32x8*)(r0 + 8);
        W0c = *(const u32x8*)(r0 + 16);
        // ---- row 1: taps 3,4,5 ----
        #pragma unroll
        for (int k = 0; k < 8; ++k) { t = W1a[k] ^ wreg[3 * 8 + k]; BCNT1(t); }
        #pragma unroll
        for (int k = 0; k < 8; ++k) { t = W1b[k] ^ wreg[4 * 8 + k]; BCNT0(t); }
        #pragma unroll
        for (int k = 0; k < 8; ++k) { t = W1c[k] ^ wreg[5 * 8 + k]; BCNT1(t); }
        r1 += 8;
        W1a = *(const u32x8*)(r1);
        W1b = *(const u32x8*)(r1 + 8);
        W1c = *(const u32x8*)(r1 + 16);
        // ---- row 2: taps 6,7,8 ----
        #pragma unroll
        for (int k = 0; k < 8; ++k) { t = W2a[k] ^ wreg[6 * 8 + k]; BCNT0(t); }
        #pragma unroll
        for (int k = 0; k < 8; ++k) { t = W2b[k] ^ wreg[7 * 8 + k]; BCNT1(t); }
        #pragma unroll
        for (int k = 0; k < 8; ++k) { t = W2c[k] ^ wreg[8 * 8 + k]; BCNT0(t); }
        r2 += 8;
        W2a = *(const u32x8*)(r2);
        W2b = *(const u32x8*)(r2 + 8);
        W2c = *(const u32x8*)(r2 + 16);

        float P = (float)(a0 + a1);
        olds[lane * 57 + (ox0 + i)] = fmaf(sAv, P, sBv);
    }

    __syncthreads();

    // Coalesced flush: 64 o-rows x 56 positions = 3584 f32 by 256 threads.
    size_t obb = ((size_t)b * OCH + obase) * HWOUT + (size_t)oy * WOUT;
    int tau = threadIdx.x;
    #pragma unroll 1
    for (int i = 0; i < 14; ++i) {
        int flat = i * 256 + tau;                // 0..3583
        int op = flat / 56;
        int pp = flat - op * 56;
        out[obb + (size_t)op * HWOUT + pp] = olds[op * 57 + pp];
    }
}

// ---------------------------------------------------------------------------
extern "C" void kernel_launch(void* const* d_in, const int* in_sizes, int n_in,
                              void* d_out, int out_size, void* d_ws, size_t ws_size,
                              hipStream_t stream)
{
    const float* x  = (const float*)d_in[0];
    const float* wt = (const float*)d_in[1];
    float* out = (float*)d_out;

    char* ws = (char*)d_ws;
    uint32_t* xp = (uint32_t*)ws;                               // 3,444,736 B
    uint32_t* wq = (uint32_t*)(ws + 3444736);                   //    73,728 B
    float*    sA = (float*)(ws + 3444736 + 73728);              //     1,024 B
    float*    sB = (float*)(ws + 3444736 + 73728 + 1024);       //     1,024 B

    // 1) pack x: 430,592 threads / 256 = 1682 blocks exactly
    pack_x_kernel<<<dim3(1682), dim3(256), 0, stream>>>(x, xp);

    // 2) pack weights (o-minor) + scales
    pack_w_kernel<<<dim3(OCH), dim3(256), 0, stream>>>(wt, wq, sA, sB);

    // 3) main: 1792 row-jobs x 4 o-groups of 64
    xnor_main_kernel<<<dim3(1792, 4), dim3(256), 0, stream>>>(xp, wq, sA, sB, out);
}

// Round 6
// 292.602 us; speedup vs baseline: 1.0349x; 1.0311x over previous
//
#include <hip/hip_runtime.h>
#include <stdint.h>

// x: (32, 256, 58, 58) f32 binary {0,1};  w: (256, 256, 3, 3) f32
// out: (32, 256, 56, 56) f32 = alpha[o]*(2S - 2304), S = XNOR matches
// out = fma(-2*alpha[o], P, 2304*alpha[o]),  P = popcount(xbits ^ wbits)

#define BATCH 32
#define C_IN 256
#define OCH 256
#define HIN 58
#define WIN2 58
#define HOUT 56
#define WOUT 56
#define TAPS 9
#define WWORDS 8            // 256 channels / 32 bits
#define HWIN (HIN * WIN2)   // 3364
#define HWOUT (HOUT * WOUT) // 3136
#define NPOS (BATCH * HWIN) // 107648

typedef unsigned int u32x8 __attribute__((ext_vector_type(8)));

// R9: fused xor+accumulate-popcount, with the weight operand pinned to the
// ARCH VGPR class ("v"; AGPRs are "a"). R5 post-mortem: VGPR_Count=40 < 72
// proves wreg lived in AGPRs -> one accvgpr copy per use = 1.5x essential
// VALU, matching measured 117us at the ~1.57GHz sustained clock. The "v"
// constraint at all 72 uses makes arch allocation the allocator's cheapest
// option. Window word is "s" (wave-uniform s_load result; v_xor src0=SGPR
// is legal, 1-SGPR rule satisfied).
#define XA0(xs, wv) { uint32_t _t;                                        \
    asm("v_xor_b32 %0, %2, %3\n\tv_bcnt_u32_b32 %1, %0, %1"               \
        : "=&v"(_t), "+v"(a0) : "s"(xs), "v"(wv)); }
#define XA1(xs, wv) { uint32_t _t;                                        \
    asm("v_xor_b32 %0, %2, %3\n\tv_bcnt_u32_b32 %1, %0, %1"               \
        : "=&v"(_t), "+v"(a1) : "s"(xs), "v"(wv)); }

// ---------------------------------------------------------------------------
// Kernel 1: bit-pack x along channels. Thread ↔ (position p, word-pair wp).
// Reads 64B-coalesced per (wp,j) group; writes fully contiguous uint2/wave.
// ---------------------------------------------------------------------------
__global__ __launch_bounds__(256) void pack_x_kernel(
    const float* __restrict__ x, uint32_t* __restrict__ xp)
{
    int t = blockIdx.x * 256 + threadIdx.x;      // 1682 blocks exactly
    int p  = t >> 2;                             // position in [0, NPOS)
    int wp = t & 3;                              // word pair
    int b = p / HWIN;
    int r = p - b * HWIN;
    const float* xb = x + ((size_t)(b * C_IN + wp * 64)) * HWIN + r;
    uint32_t m0 = 0u, m1 = 0u;
    #pragma unroll
    for (int j = 0; j < 32; ++j) {
        float v0 = xb[(size_t)j * HWIN];
        float v1 = xb[(size_t)(j + 32) * HWIN];
        m0 |= (v0 > 0.5f ? 1u : 0u) << j;        // word 2wp,   bit j = ch 64wp+j
        m1 |= (v1 > 0.5f ? 1u : 0u) << j;        // word 2wp+1, bit j = ch 64wp+32+j
    }
    *(uint2*)(xp + (size_t)p * WWORDS + wp * 2) = make_uint2(m0, m1);
}

// ---------------------------------------------------------------------------
// Kernel 2: pack weights O-MINOR: wq[(tap*8 + word)*256 + o] so the main
// kernel's per-lane (lane = o) weight loads are stride-1 coalesced.
// Also per-o scale/bias.
// ---------------------------------------------------------------------------
__global__ __launch_bounds__(256) void pack_w_kernel(
    const float* __restrict__ wt, uint32_t* __restrict__ wq,
    float* __restrict__ sA, float* __restrict__ sB)
{
    int o = blockIdx.x;
    int c = threadIdx.x;
    const float* wb = wt + ((size_t)o * C_IN + c) * TAPS;
    float wv[TAPS];
    float s = 0.f;
    #pragma unroll
    for (int t = 0; t < TAPS; ++t) {
        wv[t] = wb[t];
        s += fabsf(wv[t]);
    }
    int wave = c >> 6, lane = c & 63;
    #pragma unroll
    for (int t = 0; t < TAPS; ++t) {
        unsigned long long m = __ballot(wv[t] >= 0.0f);
        if (lane == 0) {
            // word index w2 = wave*2 holds channels wave*64..+31 (bit j = ch)
            wq[(size_t)(t * 8 + wave * 2)     * OCH + o] = (uint32_t)m;
            wq[(size_t)(t * 8 + wave * 2 + 1) * OCH + o] = (uint32_t)(m >> 32);
        }
    }
    __shared__ float red[256];
    red[c] = s;
    __syncthreads();
    for (int off = 128; off > 0; off >>= 1) {
        if (c < off) red[c] += red[c + off];
        __syncthreads();
    }
    if (c == 0) {
        float alpha = red[0] / (float)(C_IN * HWIN);   // n = C*H*W per reference
        sA[o] = -2.0f * alpha;
        sB[o] = (float)(C_IN * TAPS) * alpha;          // 2304 * alpha
    }
}

// ---------------------------------------------------------------------------
// Kernel 3: main — lane = output channel; weights forced into ARCH VGPRs.
// Structure (R7): block = 64 o (grid.y of 4) x one output row (b,oy); wave w
// owns positions [14w,14w+14). Weights: 72 dwords/lane loaded once,
// coalesced; every use carries an asm "v" constraint (see XA0/XA1).
// X-window: wave-uniform -> 72 SGPRs via s_load_dwordx8, reloaded per
// position (SMEM only, hidden under 144 VALU). Inner: exactly 2 VALU/word.
// Store: o-per-lane stores are 64-segment, so stage in LDS [64][57]
// (stride 57 odd -> bijective mod 32, inherent 2-way = free) and flush
// coalesced.
// Tail note: the last position's pipelined reload reads 32B past xp's end —
// lands in wq (same workspace, allocated), values never consumed.
// ---------------------------------------------------------------------------
__global__ __launch_bounds__(256, 4) void xnor_main_kernel(
    const uint32_t* __restrict__ xp, const uint32_t* __restrict__ wq,
    const float* __restrict__ sA, const float* __restrict__ sB,
    float* __restrict__ out)
{
    __shared__ float olds[64 * 57];              // 14,592 B

    int rj = blockIdx.x;                         // row-job 0..1791
    int b  = rj / HOUT;
    int oy = rj - b * HOUT;
    int obase = blockIdx.y * 64;
    int lane = threadIdx.x & 63;
    int wv_id = __builtin_amdgcn_readfirstlane((int)(threadIdx.x >> 6));
    int o = obase + lane;

    // Weights resident in VGPRs: 72 dwords per lane, coalesced stride-1.
    uint32_t wreg[72];
    #pragma unroll
    for (int i = 0; i < 72; ++i)
        wreg[i] = wq[(size_t)i * OCH + o];
    float sAv = sA[o];
    float sBv = sB[o];

    int ox0 = wv_id * 14;                        // this wave's first position

    // Wave-uniform row pointers (all factors uniform -> s_load path).
    const uint32_t* r0 = xp + (((size_t)b * HIN + oy + 0) * WIN2 + ox0) * WWORDS;
    const uint32_t* r1 = xp + (((size_t)b * HIN + oy + 1) * WIN2 + ox0) * WWORDS;
    const uint32_t* r2 = xp + (((size_t)b * HIN + oy + 2) * WIN2 + ox0) * WWORDS;

    // Window: rows 0..2 x cols dx=0..2, 8 words each (72 SGPRs).
    u32x8 W0a = *(const u32x8*)(r0);
    u32x8 W0b = *(const u32x8*)(r0 + 8);
    u32x8 W0c = *(const u32x8*)(r0 + 16);
    u32x8 W1a = *(const u32x8*)(r1);
    u32x8 W1b = *(const u32x8*)(r1 + 8);
    u32x8 W1c = *(const u32x8*)(r1 + 16);
    u32x8 W2a = *(const u32x8*)(r2);
    u32x8 W2b = *(const u32x8*)(r2 + 8);
    u32x8 W2c = *(const u32x8*)(r2 + 16);

    #pragma unroll 1
    for (int i = 0; i < 14; ++i) {
        uint32_t a0 = 0u, a1 = 0u;
        // ---- row 0: taps 0,1,2 ---- consume, then reload for pos+1
        #pragma unroll
        for (int k = 0; k < 8; ++k) XA0(W0a[k], wreg[0 * 8 + k]);
        #pragma unroll
        for (int k = 0; k < 8; ++k) XA1(W0b[k], wreg[1 * 8 + k]);
        #pragma unroll
        for (int k = 0; k < 8; ++k) XA0(W0c[k], wreg[2 * 8 + k]);
        r0 += 8;
        W0a = *(const u32x8*)(r0);
        W0b = *(const u32x8*)(r0 + 8);
        W0c = *(const u32x8*)(r0 + 16);
        // ---- row 1: taps 3,4,5 ----
        #pragma unroll
        for (int k = 0; k < 8; ++k) XA1(W1a[k], wreg[3 * 8 + k]);
        #pragma unroll
        for (int k = 0; k < 8; ++k) XA0(W1b[k], wreg[4 * 8 + k]);
        #pragma unroll
        for (int k = 0; k < 8; ++k) XA1(W1c[k], wreg[5 * 8 + k]);
        r1 += 8;
        W1a = *(const u32x8*)(r1);
        W1b = *(const u32x8*)(r1 + 8);
        W1c = *(const u32x8*)(r1 + 16);
        // ---- row 2: taps 6,7,8 ----
        #pragma unroll
        for (int k = 0; k < 8; ++k) XA0(W2a[k], wreg[6 * 8 + k]);
        #pragma unroll
        for (int k = 0; k < 8; ++k) XA1(W2b[k], wreg[7 * 8 + k]);
        #pragma unroll
        for (int k = 0; k < 8; ++k) XA0(W2c[k], wreg[8 * 8 + k]);
        r2 += 8;
        W2a = *(const u32x8*)(r2);
        W2b = *(const u32x8*)(r2 + 8);
        W2c = *(const u32x8*)(r2 + 16);

        float P = (float)(a0 + a1);
        olds[lane * 57 + (ox0 + i)] = fmaf(sAv, P, sBv);
    }

    __syncthreads();

    // Coalesced flush: 64 o-rows x 56 positions = 3584 f32 by 256 threads.
    size_t obb = ((size_t)b * OCH + obase) * HWOUT + (size_t)oy * WOUT;
    int tau = threadIdx.x;
    #pragma unroll 1
    for (int i = 0; i < 14; ++i) {
        int flat = i * 256 + tau;                // 0..3583
        int op = flat / 56;
        int pp = flat - op * 56;
        out[obb + (size_t)op * HWOUT + pp] = olds[op * 57 + pp];
    }
}

// ---------------------------------------------------------------------------
extern "C" void kernel_launch(void* const* d_in, const int* in_sizes, int n_in,
                              void* d_out, int out_size, void* d_ws, size_t ws_size,
                              hipStream_t stream)
{
    const float* x  = (const float*)d_in[0];
    const float* wt = (const float*)d_in[1];
    float* out = (float*)d_out;

    char* ws = (char*)d_ws;
    uint32_t* xp = (uint32_t*)ws;                               // 3,444,736 B
    uint32_t* wq = (uint32_t*)(ws + 3444736);                   //    73,728 B
    float*    sA = (float*)(ws + 3444736 + 73728);              //     1,024 B
    float*    sB = (float*)(ws + 3444736 + 73728 + 1024);       //     1,024 B

    // 1) pack x: 430,592 threads / 256 = 1682 blocks exactly
    pack_x_kernel<<<dim3(1682), dim3(256), 0, stream>>>(x, xp);

    // 2) pack weights (o-minor) + scales
    pack_w_kernel<<<dim3(OCH), dim3(256), 0, stream>>>(wt, wq, sA, sB);

    // 3) main: 1792 row-jobs x 4 o-groups of 64
    xnor_main_kernel<<<dim3(1792, 4), dim3(256), 0, stream>>>(xp, wq, sA, sB, out);
}